// Round 1
// baseline (273.514 us; speedup 1.0000x reference)
//
#include <hip/hip_runtime.h>

#define NB 8192
#define EPS_BN 1e-5f

// ---------------------------------------------------------------------------
// Kernel 1: conv1(1->8,k7,s4,p3) -> BN -> ReLU
//           conv2(8->16,k5,s4,p2) -> BN -> ReLU
//           conv3(16->32,k3,s2,p1) -> BN -> ReLU
//           spatial mean (written to d_out) + LIF scan -> bit-packed spikes
// One block (256 threads) per batch element.
// ---------------------------------------------------------------------------
__global__ __launch_bounds__(256) void conv_lif_kernel(
    const float* __restrict__ x,
    const float* __restrict__ w1, const float* __restrict__ b1,
    const float* __restrict__ g1, const float* __restrict__ be1,
    const float* __restrict__ m1, const float* __restrict__ v1,
    const float* __restrict__ w2, const float* __restrict__ b2,
    const float* __restrict__ g2, const float* __restrict__ be2,
    const float* __restrict__ m2, const float* __restrict__ v2,
    const float* __restrict__ w3, const float* __restrict__ b3,
    const float* __restrict__ g3, const float* __restrict__ be3,
    const float* __restrict__ m3, const float* __restrict__ v3,
    float* __restrict__ spatial_out,        // [B][32]
    unsigned int* __restrict__ spk)         // [32][B]  (t-major, coalesced for LSTM)
{
    __shared__ float xs[1024];
    __shared__ float c1[8][256];
    __shared__ float c2[16][64];
    __shared__ float c3[32][33];            // +1 pad: kills 32-way conflict on LIF/mean reads
    __shared__ float wA[56];
    __shared__ float sc1[8], bi1[8];
    __shared__ float wB[640];
    __shared__ float sc2[16], bi2[16];
    __shared__ float wC[1536];
    __shared__ float sc3[32], bi3[32];

    const int b   = blockIdx.x;
    const int tid = threadIdx.x;

    // stage weights + fold BN:  y = conv*inv + ((b-m)*inv + be)
    if (tid < 56) wA[tid] = w1[tid];
    for (int i = tid; i < 640;  i += 256) wB[i] = w2[i];
    for (int i = tid; i < 1536; i += 256) wC[i] = w3[i];
    if (tid < 8) {
        float inv = g1[tid] * rsqrtf(v1[tid] + EPS_BN);
        sc1[tid] = inv; bi1[tid] = (b1[tid] - m1[tid]) * inv + be1[tid];
    } else if (tid >= 64 && tid < 80) {
        int c = tid - 64;
        float inv = g2[c] * rsqrtf(v2[c] + EPS_BN);
        sc2[c] = inv; bi2[c] = (b2[c] - m2[c]) * inv + be2[c];
    } else if (tid >= 128 && tid < 160) {
        int c = tid - 128;
        float inv = g3[c] * rsqrtf(v3[c] + EPS_BN);
        sc3[c] = inv; bi3[c] = (b3[c] - m3[c]) * inv + be3[c];
    }

    // stage x (coalesced float4)
    reinterpret_cast<float4*>(xs)[tid] =
        reinterpret_cast<const float4*>(x + (size_t)b * 1024)[tid];
    __syncthreads();

    // conv1: 8 ch x 256 pos
    for (int idx = tid; idx < 2048; idx += 256) {
        int t = idx & 255, c = idx >> 8;
        int base = 4 * t - 3;
        float acc = 0.f;
        #pragma unroll
        for (int k = 0; k < 7; k++) {
            int ii = base + k;
            float xv = (ii >= 0 && ii < 1024) ? xs[ii] : 0.f;
            acc = fmaf(wA[c * 7 + k], xv, acc);
        }
        acc = fmaf(acc, sc1[c], bi1[c]);
        c1[c][t] = fmaxf(acc, 0.f);
    }
    __syncthreads();

    // conv2: 16 ch x 64 pos
    for (int idx = tid; idx < 1024; idx += 256) {
        int t = idx & 63, c = idx >> 6;
        int base = 4 * t - 2;
        float acc = 0.f;
        #pragma unroll
        for (int ci = 0; ci < 8; ci++) {
            #pragma unroll
            for (int k = 0; k < 5; k++) {
                int ii = base + k;
                float vv = (ii >= 0 && ii < 256) ? c1[ci][ii] : 0.f;
                acc = fmaf(wB[(c * 8 + ci) * 5 + k], vv, acc);
            }
        }
        acc = fmaf(acc, sc2[c], bi2[c]);
        c2[c][t] = fmaxf(acc, 0.f);
    }
    __syncthreads();

    // conv3: 32 ch x 32 pos
    for (int idx = tid; idx < 1024; idx += 256) {
        int t = idx & 31, c = idx >> 5;
        int base = 2 * t - 1;
        float acc = 0.f;
        #pragma unroll
        for (int ci = 0; ci < 16; ci++) {
            #pragma unroll
            for (int k = 0; k < 3; k++) {
                int ii = base + k;
                float vv = (ii >= 0 && ii < 64) ? c2[ci][ii] : 0.f;
                acc = fmaf(wC[(c * 16 + ci) * 3 + k], vv, acc);
            }
        }
        acc = fmaf(acc, sc3[c], bi3[c]);
        c3[c][t] = fmaxf(acc, 0.f);
    }
    __syncthreads();

    // spatial mean + LIF scan (lanes 0..31 of wave 0)
    if (tid < 32) {
        float s = 0.f;
        #pragma unroll
        for (int t = 0; t < 32; t++) s += c3[tid][t];
        spatial_out[(size_t)b * 32 + tid] = s * 0.03125f;

        float mem = 0.f;
        #pragma unroll
        for (int t = 0; t < 32; t++) {
            // unfused to match numpy's round(0.9*mem) then round(+x)
            mem = __fadd_rn(__fmul_rn(0.9f, mem), c3[tid][t]);
            bool spike = mem > 0.5f;
            mem = spike ? 0.f : mem;
            unsigned long long msk = __ballot(spike);   // lanes 32..63 inactive -> 0
            if (tid == 0) spk[(size_t)t * NB + b] = (unsigned int)(msk & 0xffffffffull);
        }
    }
}

// ---------------------------------------------------------------------------
// Kernel 2: 32-step LSTM (spike inputs as bitmasks) + fused FC head.
// 128 threads = one gate row per thread; weight rows live in VGPRs.
// Each block loops over NB/gridDim batches sequentially.
// ---------------------------------------------------------------------------
__global__ __launch_bounds__(128) void lstm_fc_kernel(
    const unsigned int* __restrict__ spk,   // [32][B]
    const float* __restrict__ w_ih, const float* __restrict__ w_hh,
    const float* __restrict__ b_ih, const float* __restrict__ b_hh,
    const float* __restrict__ fc1w, const float* __restrict__ fc1b,
    const float* __restrict__ fc2w, const float* __restrict__ fc2b,
    const float* __restrict__ fc3w, const float* __restrict__ fc3b,
    const float* __restrict__ spatial_in,   // [B][32] (from d_out)
    float* __restrict__ out0,               // [B][4]
    float* __restrict__ hlast_out)          // [B][32]
{
    const int g = threadIdx.x;              // gate row 0..127
    const int gtype = g >> 5;               // 0:i 1:f 2:g 3:o

    float wi[32], wh[32];
    #pragma unroll
    for (int q = 0; q < 8; q++) {
        float4 a = reinterpret_cast<const float4*>(w_ih)[g * 8 + q];
        wi[4*q+0] = a.x; wi[4*q+1] = a.y; wi[4*q+2] = a.z; wi[4*q+3] = a.w;
        float4 c = reinterpret_cast<const float4*>(w_hh)[g * 8 + q];
        wh[4*q+0] = c.x; wh[4*q+1] = c.y; wh[4*q+2] = c.z; wh[4*q+3] = c.w;
    }
    const float bias = b_ih[g] + b_hh[g];

    __shared__ alignas(16) float h_lds[32];
    __shared__ float gact[128];
    __shared__ float comb[64];
    __shared__ float z1[64];
    __shared__ float z2[32];

    for (int b = blockIdx.x; b < NB; b += gridDim.x) {
        if (g < 32) h_lds[g] = 0.f;
        float cst = 0.f;
        __syncthreads();

        #pragma unroll 1
        for (int t = 0; t < 32; t++) {
            const unsigned int s = spk[(size_t)t * NB + b];   // uniform -> scalar load
            float acc = bias;
            #pragma unroll
            for (int f = 0; f < 32; f++)
                acc += (s & (1u << f)) ? wi[f] : 0.f;
            #pragma unroll
            for (int k = 0; k < 8; k++) {
                float4 h4 = reinterpret_cast<const float4*>(h_lds)[k];  // broadcast
                acc = fmaf(wh[4*k+0], h4.x, acc);
                acc = fmaf(wh[4*k+1], h4.y, acc);
                acc = fmaf(wh[4*k+2], h4.z, acc);
                acc = fmaf(wh[4*k+3], h4.w, acc);
            }
            gact[g] = (gtype == 2) ? tanhf(acc) : 1.f / (1.f + __expf(-acc));
            __syncthreads();
            if (g < 32) {
                float iv = gact[g], fv = gact[g + 32], gv = gact[g + 64], ov = gact[g + 96];
                cst = fmaf(fv, cst, iv * gv);
                h_lds[g] = ov * tanhf(cst);
            }
            __syncthreads();
        }

        // FC head: combined = [h_last, spatial]
        if (g < 32) {
            hlast_out[(size_t)b * 32 + g] = h_lds[g];
            comb[g] = h_lds[g];
        } else if (g < 64) {
            comb[g] = spatial_in[(size_t)b * 32 + (g - 32)];
        }
        __syncthreads();
        if (g < 64) {
            float acc = fc1b[g];
            #pragma unroll
            for (int k = 0; k < 64; k++) acc = fmaf(fc1w[g * 64 + k], comb[k], acc);
            z1[g] = fmaxf(acc, 0.f);
        }
        __syncthreads();
        if (g < 32) {
            float acc = fc2b[g];
            #pragma unroll
            for (int k = 0; k < 64; k++) acc = fmaf(fc2w[g * 64 + k], z1[k], acc);
            z2[g] = fmaxf(acc, 0.f);
        }
        __syncthreads();
        if (g < 4) {
            float acc = fc3b[g];
            #pragma unroll
            for (int k = 0; k < 32; k++) acc = fmaf(fc3w[g * 32 + k], z2[k], acc);
            out0[(size_t)b * 4 + g] = acc;
        }
        __syncthreads();   // before LDS reuse for next batch
    }
}

// ---------------------------------------------------------------------------
extern "C" void kernel_launch(void* const* d_in, const int* in_sizes, int n_in,
                              void* d_out, int out_size, void* d_ws, size_t ws_size,
                              hipStream_t stream) {
    const float* x    = (const float*)d_in[0];
    const float* w1   = (const float*)d_in[1];
    const float* b1   = (const float*)d_in[2];
    const float* g1   = (const float*)d_in[3];
    const float* be1  = (const float*)d_in[4];
    const float* m1   = (const float*)d_in[5];
    const float* v1   = (const float*)d_in[6];
    const float* w2   = (const float*)d_in[7];
    const float* b2   = (const float*)d_in[8];
    const float* g2   = (const float*)d_in[9];
    const float* be2  = (const float*)d_in[10];
    const float* m2   = (const float*)d_in[11];
    const float* v2   = (const float*)d_in[12];
    const float* w3   = (const float*)d_in[13];
    const float* b3   = (const float*)d_in[14];
    const float* g3   = (const float*)d_in[15];
    const float* be3  = (const float*)d_in[16];
    const float* m3   = (const float*)d_in[17];
    const float* v3   = (const float*)d_in[18];
    const float* w_ih = (const float*)d_in[19];
    const float* w_hh = (const float*)d_in[20];
    const float* b_ih = (const float*)d_in[21];
    const float* b_hh = (const float*)d_in[22];
    const float* fc1w = (const float*)d_in[23];
    const float* fc1b = (const float*)d_in[24];
    const float* fc2w = (const float*)d_in[25];
    const float* fc2b = (const float*)d_in[26];
    const float* fc3w = (const float*)d_in[27];
    const float* fc3b = (const float*)d_in[28];

    float* out0    = (float*)d_out;                 // [8192][4]
    float* spatial = out0 + (size_t)NB * 4;         // [8192][32]
    float* hlast   = spatial + (size_t)NB * 32;     // [8192][32]
    unsigned int* spk = (unsigned int*)d_ws;        // [32][8192] bit-packed spikes

    hipLaunchKernelGGL(conv_lif_kernel, dim3(NB), dim3(256), 0, stream,
                       x, w1, b1, g1, be1, m1, v1,
                       w2, b2, g2, be2, m2, v2,
                       w3, b3, g3, be3, m3, v3,
                       spatial, spk);

    hipLaunchKernelGGL(lstm_fc_kernel, dim3(2048), dim3(128), 0, stream,
                       spk, w_ih, w_hh, b_ih, b_hh,
                       fc1w, fc1b, fc2w, fc2b, fc3w, fc3b,
                       spatial, out0, hlast);
}

// Round 2
// 236.509 us; speedup vs baseline: 1.1565x; 1.1565x over previous
//
#include <hip/hip_runtime.h>

#define NB 8192
#define EPS_BN 1e-5f

// ---------------------------------------------------------------------------
// Kernel 1: conv1(1->8,k7,s4,p3) -> BN -> ReLU
//           conv2(8->16,k5,s4,p2) -> BN -> ReLU
//           conv3(16->32,k3,s2,p1) -> BN -> ReLU
//           spatial mean + LIF scan -> bit-packed spikes [B][32]
// One block (256 threads) per batch element. Zero-padded LDS => no bounds
// checks; position-owner threads => window values reused across channels.
// ---------------------------------------------------------------------------
__global__ __launch_bounds__(256) void conv_lif_kernel(
    const float* __restrict__ x,
    const float* __restrict__ w1, const float* __restrict__ b1,
    const float* __restrict__ g1, const float* __restrict__ be1,
    const float* __restrict__ m1, const float* __restrict__ v1,
    const float* __restrict__ w2, const float* __restrict__ b2,
    const float* __restrict__ g2, const float* __restrict__ be2,
    const float* __restrict__ m2, const float* __restrict__ v2,
    const float* __restrict__ w3, const float* __restrict__ b3,
    const float* __restrict__ g3, const float* __restrict__ be3,
    const float* __restrict__ m3, const float* __restrict__ v3,
    float* __restrict__ spatial_out,        // [B][32]
    unsigned int* __restrict__ spk)         // [B][32] bitmask per (b,t)
{
    __shared__ alignas(16) float xs[1040];      // [8 zero | 1024 data | 8 zero]
    __shared__ alignas(16) float c1[8][264];    // [2 zero | 256 data | slack]
    __shared__ alignas(16) float c2[16][68];    // [1 zero | 64 data | slack]
    __shared__ alignas(16) float c3[32][33];    // +1 pad for LIF column reads
    __shared__ float wA[56];
    __shared__ float sc1[8], bi1[8];
    __shared__ float wB[640];
    __shared__ float sc2[16], bi2[16];
    __shared__ float wC[1536];
    __shared__ float sc3[32], bi3[32];

    const int b   = blockIdx.x;
    const int tid = threadIdx.x;

    // ---- stage weights, fold BN, zero pads ----
    if (tid < 56) wA[tid] = w1[tid];
    for (int i = tid; i < 640;  i += 256) wB[i] = w2[i];
    for (int i = tid; i < 1536; i += 256) wC[i] = w3[i];
    if (tid < 8) {
        float inv = g1[tid] * rsqrtf(v1[tid] + EPS_BN);
        sc1[tid] = inv; bi1[tid] = (b1[tid] - m1[tid]) * inv + be1[tid];
        xs[tid] = 0.f; xs[1032 + tid] = 0.f;
    } else if (tid >= 64 && tid < 80) {
        int c = tid - 64;
        float inv = g2[c] * rsqrtf(v2[c] + EPS_BN);
        sc2[c] = inv; bi2[c] = (b2[c] - m2[c]) * inv + be2[c];
    } else if (tid >= 128 && tid < 160) {
        int c = tid - 128;
        float inv = g3[c] * rsqrtf(v3[c] + EPS_BN);
        sc3[c] = inv; bi3[c] = (b3[c] - m3[c]) * inv + be3[c];
    } else if (tid >= 192 && tid < 208) {
        int j = tid - 192;                  // 16 jobs: c1 pads (8 rows x 2)
        c1[j >> 1][j & 1] = 0.f;
    } else if (tid >= 224 && tid < 240) {
        c2[tid - 224][0] = 0.f;             // c2 front pads (16 rows)
    }

    // stage x (coalesced float4) at offset 8
    reinterpret_cast<float4*>(xs + 8)[tid] =
        reinterpret_cast<const float4*>(x + (size_t)b * 1024)[tid];
    __syncthreads();

    // ---- conv1: thread = output position t (256), all 8 channels ----
    {
        const int t = tid;
        float4 xa = *reinterpret_cast<const float4*>(&xs[4 * t + 4]);
        float4 xb = *reinterpret_cast<const float4*>(&xs[4 * t + 8]);
        float win[7] = {xa.y, xa.z, xa.w, xb.x, xb.y, xb.z, xb.w};
        #pragma unroll
        for (int c = 0; c < 8; c++) {
            float acc = 0.f;
            #pragma unroll
            for (int k = 0; k < 7; k++) acc = fmaf(wA[c * 7 + k], win[k], acc);
            acc = fmaf(acc, sc1[c], bi1[c]);
            c1[c][2 + t] = fmaxf(acc, 0.f);
        }
    }
    __syncthreads();

    // ---- conv2: thread = (pos t2 of 64, channel group of 4) ----
    {
        const int t2 = tid >> 2, cg = (tid & 3) * 4;
        float a0 = 0.f, a1 = 0.f, a2 = 0.f, a3 = 0.f;
        #pragma unroll
        for (int ci = 0; ci < 8; ci++) {
            float4 va = *reinterpret_cast<const float4*>(&c1[ci][4 * t2]);
            float  v4 = c1[ci][4 * t2 + 4];
            float w0[5], w1_[5], w2_[5], w3_[5];
            #pragma unroll
            for (int k = 0; k < 5; k++) {
                w0[k]  = wB[((cg + 0) * 8 + ci) * 5 + k];
                w1_[k] = wB[((cg + 1) * 8 + ci) * 5 + k];
                w2_[k] = wB[((cg + 2) * 8 + ci) * 5 + k];
                w3_[k] = wB[((cg + 3) * 8 + ci) * 5 + k];
            }
            a0 = fmaf(w0[0], va.x, a0); a0 = fmaf(w0[1], va.y, a0);
            a0 = fmaf(w0[2], va.z, a0); a0 = fmaf(w0[3], va.w, a0);
            a0 = fmaf(w0[4], v4,  a0);
            a1 = fmaf(w1_[0], va.x, a1); a1 = fmaf(w1_[1], va.y, a1);
            a1 = fmaf(w1_[2], va.z, a1); a1 = fmaf(w1_[3], va.w, a1);
            a1 = fmaf(w1_[4], v4,  a1);
            a2 = fmaf(w2_[0], va.x, a2); a2 = fmaf(w2_[1], va.y, a2);
            a2 = fmaf(w2_[2], va.z, a2); a2 = fmaf(w2_[3], va.w, a2);
            a2 = fmaf(w2_[4], v4,  a2);
            a3 = fmaf(w3_[0], va.x, a3); a3 = fmaf(w3_[1], va.y, a3);
            a3 = fmaf(w3_[2], va.z, a3); a3 = fmaf(w3_[3], va.w, a3);
            a3 = fmaf(w3_[4], v4,  a3);
        }
        c2[cg + 0][1 + t2] = fmaxf(fmaf(a0, sc2[cg + 0], bi2[cg + 0]), 0.f);
        c2[cg + 1][1 + t2] = fmaxf(fmaf(a1, sc2[cg + 1], bi2[cg + 1]), 0.f);
        c2[cg + 2][1 + t2] = fmaxf(fmaf(a2, sc2[cg + 2], bi2[cg + 2]), 0.f);
        c2[cg + 3][1 + t2] = fmaxf(fmaf(a3, sc2[cg + 3], bi2[cg + 3]), 0.f);
    }
    __syncthreads();

    // ---- conv3: thread = (pos t3 of 32, channel group of 4) ----
    {
        const int t3 = tid >> 3, cg = (tid & 7) * 4;
        float a0 = 0.f, a1 = 0.f, a2 = 0.f, a3 = 0.f;
        #pragma unroll
        for (int ci = 0; ci < 16; ci++) {
            float2 vab = *reinterpret_cast<const float2*>(&c2[ci][2 * t3]);
            float  vc  = c2[ci][2 * t3 + 2];
            #pragma unroll
            for (int j = 0; j < 1; j++) { }   // (keep structure flat)
            float w00 = wC[((cg + 0) * 16 + ci) * 3 + 0];
            float w01 = wC[((cg + 0) * 16 + ci) * 3 + 1];
            float w02 = wC[((cg + 0) * 16 + ci) * 3 + 2];
            float w10 = wC[((cg + 1) * 16 + ci) * 3 + 0];
            float w11 = wC[((cg + 1) * 16 + ci) * 3 + 1];
            float w12 = wC[((cg + 1) * 16 + ci) * 3 + 2];
            float w20 = wC[((cg + 2) * 16 + ci) * 3 + 0];
            float w21 = wC[((cg + 2) * 16 + ci) * 3 + 1];
            float w22 = wC[((cg + 2) * 16 + ci) * 3 + 2];
            float w30 = wC[((cg + 3) * 16 + ci) * 3 + 0];
            float w31 = wC[((cg + 3) * 16 + ci) * 3 + 1];
            float w32 = wC[((cg + 3) * 16 + ci) * 3 + 2];
            a0 = fmaf(w00, vab.x, a0); a0 = fmaf(w01, vab.y, a0); a0 = fmaf(w02, vc, a0);
            a1 = fmaf(w10, vab.x, a1); a1 = fmaf(w11, vab.y, a1); a1 = fmaf(w12, vc, a1);
            a2 = fmaf(w20, vab.x, a2); a2 = fmaf(w21, vab.y, a2); a2 = fmaf(w22, vc, a2);
            a3 = fmaf(w30, vab.x, a3); a3 = fmaf(w31, vab.y, a3); a3 = fmaf(w32, vc, a3);
        }
        c3[cg + 0][t3] = fmaxf(fmaf(a0, sc3[cg + 0], bi3[cg + 0]), 0.f);
        c3[cg + 1][t3] = fmaxf(fmaf(a1, sc3[cg + 1], bi3[cg + 1]), 0.f);
        c3[cg + 2][t3] = fmaxf(fmaf(a2, sc3[cg + 2], bi3[cg + 2]), 0.f);
        c3[cg + 3][t3] = fmaxf(fmaf(a3, sc3[cg + 3], bi3[cg + 3]), 0.f);
    }
    __syncthreads();

    // ---- spatial mean + LIF scan (lanes 0..31 of wave 0) ----
    if (tid < 32) {
        float s = 0.f;
        #pragma unroll
        for (int t = 0; t < 32; t++) s += c3[tid][t];
        spatial_out[(size_t)b * 32 + tid] = s * 0.03125f;

        float mem = 0.f;
        #pragma unroll
        for (int t = 0; t < 32; t++) {
            mem = __fadd_rn(__fmul_rn(0.9f, mem), c3[tid][t]);
            bool spike = mem > 0.5f;
            mem = spike ? 0.f : mem;
            unsigned long long msk = __ballot(spike);
            if (tid == 0) spk[(size_t)b * 32 + t] = (unsigned int)(msk & 0xffffffffull);
        }
    }
}

// ---------------------------------------------------------------------------
// Kernel 2: 32-step LSTM + fused FC head. ONE WAVE (64 threads) per batch;
// lane l owns gate rows l (i/f) and l+64 (g/o). No barriers in the time loop
// (single wave => LDS ops are program-ordered). Binary input projection uses
// wave-uniform SALU mask->float (0x3f800000 * bit) => FMA with SGPR operand.
// ---------------------------------------------------------------------------
__global__ __launch_bounds__(64, 2) void lstm_fc_kernel(
    const unsigned int* __restrict__ spk,   // [B][32]
    const float* __restrict__ w_ih, const float* __restrict__ w_hh,
    const float* __restrict__ b_ih, const float* __restrict__ b_hh,
    const float* __restrict__ fc1w, const float* __restrict__ fc1b,
    const float* __restrict__ fc2w, const float* __restrict__ fc2b,
    const float* __restrict__ fc3w, const float* __restrict__ fc3b,
    const float* __restrict__ spatial_in,   // [B][32]
    float* __restrict__ out0,               // [B][4]
    float* __restrict__ hlast_out)          // [B][32]
{
    const int l  = threadIdx.x;             // 0..63
    const int r0 = l;                       // i (l<32) / f (l>=32)
    const int r1 = l + 64;                  // g (l<32) / o (l>=32)

    float wi0[32], wh0[32], wi1[32], wh1[32];
    #pragma unroll
    for (int q = 0; q < 8; q++) {
        float4 a = reinterpret_cast<const float4*>(w_ih + r0 * 32)[q];
        wi0[4*q+0] = a.x; wi0[4*q+1] = a.y; wi0[4*q+2] = a.z; wi0[4*q+3] = a.w;
        float4 c = reinterpret_cast<const float4*>(w_hh + r0 * 32)[q];
        wh0[4*q+0] = c.x; wh0[4*q+1] = c.y; wh0[4*q+2] = c.z; wh0[4*q+3] = c.w;
        float4 e = reinterpret_cast<const float4*>(w_ih + r1 * 32)[q];
        wi1[4*q+0] = e.x; wi1[4*q+1] = e.y; wi1[4*q+2] = e.z; wi1[4*q+3] = e.w;
        float4 f = reinterpret_cast<const float4*>(w_hh + r1 * 32)[q];
        wh1[4*q+0] = f.x; wh1[4*q+1] = f.y; wh1[4*q+2] = f.z; wh1[4*q+3] = f.w;
    }
    const float bias0 = b_ih[r0] + b_hh[r0];
    const float bias1 = b_ih[r1] + b_hh[r1];
    // act1 = a1m * sigmoid(a1s * x) + a1c :  tanh for l<32, sigmoid for l>=32
    const float a1s = (l < 32) ? 2.f : 1.f;
    const float a1m = (l < 32) ? 2.f : 1.f;
    const float a1c = (l < 32) ? -1.f : 0.f;

    __shared__ alignas(16) float hbuf[32];
    __shared__ alignas(16) float z1b[64];
    __shared__ alignas(16) float z2b[32];

    for (int b = blockIdx.x; b < NB; b += 2048) {
        const unsigned int* mrow = spk + (size_t)b * 32;
        if (l < 32) hbuf[l] = 0.f;
        float cst = 0.f;
        float h = 0.f;

        unsigned int s_cur = mrow[0];
        #pragma unroll 1
        for (int t = 0; t < 32; t++) {
            unsigned int s_nxt = (t < 31) ? mrow[t + 1] : 0u;
            float p0 = bias0, q0 = 0.f;     // two chains per row for ILP
            float p1 = bias1, q1 = 0.f;
            // hidden projection: broadcast LDS reads
            #pragma unroll
            for (int k = 0; k < 8; k++) {
                float4 h4 = reinterpret_cast<const float4*>(hbuf)[k];
                p0 = fmaf(wh0[4*k+0], h4.x, p0); q0 = fmaf(wh0[4*k+1], h4.y, q0);
                p0 = fmaf(wh0[4*k+2], h4.z, p0); q0 = fmaf(wh0[4*k+3], h4.w, q0);
                p1 = fmaf(wh1[4*k+0], h4.x, p1); q1 = fmaf(wh1[4*k+1], h4.y, q1);
                p1 = fmaf(wh1[4*k+2], h4.z, p1); q1 = fmaf(wh1[4*k+3], h4.w, q1);
            }
            // input projection: uniform mask -> float on the SCALAR side
            #pragma unroll
            for (int ff = 0; ff < 32; ff += 2) {
                float xf0 = __uint_as_float(((s_cur >> ff) & 1u) * 0x3f800000u);
                float xf1 = __uint_as_float(((s_cur >> (ff + 1)) & 1u) * 0x3f800000u);
                p0 = fmaf(xf0, wi0[ff], p0);   q0 = fmaf(xf1, wi0[ff + 1], q0);
                p1 = fmaf(xf0, wi1[ff], p1);   q1 = fmaf(xf1, wi1[ff + 1], q1);
            }
            float acc0 = p0 + q0;
            float acc1 = p1 + q1;
            // activations (exp+rcp; saturation-safe)
            float act0 = __builtin_amdgcn_rcpf(1.f + __expf(-acc0));          // sig(i|f)
            float act1 = fmaf(a1m, __builtin_amdgcn_rcpf(1.f + __expf(-a1s * acc1)), a1c);
            float fv = __shfl_xor(act0, 32);   // sigmoid(f) for l<32
            float ov = __shfl_xor(act1, 32);   // sigmoid(o) for l<32
            cst = fmaf(fv, cst, act0 * act1);  // f*c + i*g   (valid l<32)
            float th = fmaf(2.f, __builtin_amdgcn_rcpf(1.f + __expf(-2.f * cst)), -1.f);
            h = ov * th;
            if (l < 32) hbuf[l] = h;           // single wave: program-ordered
            s_cur = s_nxt;
        }

        // ---- FC head (single wave, LDS program-ordered) ----
        if (l < 32) hlast_out[(size_t)b * 32 + l] = h;

        float accA = fc1b[l], accB = 0.f;
        #pragma unroll
        for (int q = 0; q < 8; q++) {
            float4 hv = reinterpret_cast<const float4*>(hbuf)[q];
            float4 wv = reinterpret_cast<const float4*>(fc1w + l * 64)[q];
            accA = fmaf(wv.x, hv.x, accA); accB = fmaf(wv.y, hv.y, accB);
            accA = fmaf(wv.z, hv.z, accA); accB = fmaf(wv.w, hv.w, accB);
        }
        #pragma unroll
        for (int q = 0; q < 8; q++) {
            float4 sv = reinterpret_cast<const float4*>(spatial_in + (size_t)b * 32)[q];
            float4 wv = reinterpret_cast<const float4*>(fc1w + l * 64 + 32)[q];
            accA = fmaf(wv.x, sv.x, accA); accB = fmaf(wv.y, sv.y, accB);
            accA = fmaf(wv.z, sv.z, accA); accB = fmaf(wv.w, sv.w, accB);
        }
        z1b[l] = fmaxf(accA + accB, 0.f);

        if (l < 32) {
            float aA = fc2b[l], aB = 0.f;
            #pragma unroll
            for (int q = 0; q < 16; q++) {
                float4 zv = reinterpret_cast<const float4*>(z1b)[q];
                float4 wv = reinterpret_cast<const float4*>(fc2w + l * 64)[q];
                aA = fmaf(wv.x, zv.x, aA); aB = fmaf(wv.y, zv.y, aB);
                aA = fmaf(wv.z, zv.z, aA); aB = fmaf(wv.w, zv.w, aB);
            }
            z2b[l] = fmaxf(aA + aB, 0.f);
        }
        if (l < 4) {
            float aA = fc3b[l], aB = 0.f;
            #pragma unroll
            for (int q = 0; q < 8; q++) {
                float4 zv = reinterpret_cast<const float4*>(z2b)[q];
                float4 wv = reinterpret_cast<const float4*>(fc3w + l * 32)[q];
                aA = fmaf(wv.x, zv.x, aA); aB = fmaf(wv.y, zv.y, aB);
                aA = fmaf(wv.z, zv.z, aA); aB = fmaf(wv.w, zv.w, aB);
            }
            out0[(size_t)b * 4 + l] = aA + aB;
        }
    }
}

// ---------------------------------------------------------------------------
extern "C" void kernel_launch(void* const* d_in, const int* in_sizes, int n_in,
                              void* d_out, int out_size, void* d_ws, size_t ws_size,
                              hipStream_t stream) {
    const float* x    = (const float*)d_in[0];
    const float* w1   = (const float*)d_in[1];
    const float* b1   = (const float*)d_in[2];
    const float* g1   = (const float*)d_in[3];
    const float* be1  = (const float*)d_in[4];
    const float* m1   = (const float*)d_in[5];
    const float* v1   = (const float*)d_in[6];
    const float* w2   = (const float*)d_in[7];
    const float* b2   = (const float*)d_in[8];
    const float* g2   = (const float*)d_in[9];
    const float* be2  = (const float*)d_in[10];
    const float* m2   = (const float*)d_in[11];
    const float* v2   = (const float*)d_in[12];
    const float* w3   = (const float*)d_in[13];
    const float* b3   = (const float*)d_in[14];
    const float* g3   = (const float*)d_in[15];
    const float* be3  = (const float*)d_in[16];
    const float* m3   = (const float*)d_in[17];
    const float* v3   = (const float*)d_in[18];
    const float* w_ih = (const float*)d_in[19];
    const float* w_hh = (const float*)d_in[20];
    const float* b_ih = (const float*)d_in[21];
    const float* b_hh = (const float*)d_in[22];
    const float* fc1w = (const float*)d_in[23];
    const float* fc1b = (const float*)d_in[24];
    const float* fc2w = (const float*)d_in[25];
    const float* fc2b = (const float*)d_in[26];
    const float* fc3w = (const float*)d_in[27];
    const float* fc3b = (const float*)d_in[28];

    float* out0    = (float*)d_out;                 // [8192][4]
    float* spatial = out0 + (size_t)NB * 4;         // [8192][32]
    float* hlast   = spatial + (size_t)NB * 32;     // [8192][32]
    unsigned int* spk = (unsigned int*)d_ws;        // [8192][32] bitmasks

    hipLaunchKernelGGL(conv_lif_kernel, dim3(NB), dim3(256), 0, stream,
                       x, w1, b1, g1, be1, m1, v1,
                       w2, b2, g2, be2, m2, v2,
                       w3, b3, g3, be3, m3, v3,
                       spatial, spk);

    hipLaunchKernelGGL(lstm_fc_kernel, dim3(2048), dim3(64), 0, stream,
                       spk, w_ih, w_hh, b_ih, b_hh,
                       fc1w, fc1b, fc2w, fc2b, fc3w, fc3b,
                       spatial, out0, hlast);
}

// Round 3
// 164.554 us; speedup vs baseline: 1.6621x; 1.4373x over previous
//
#include <hip/hip_runtime.h>

#define NB 8192
#define EPS_BN 1e-5f

// padded LDS index: +4 floats every 32 => stride-16B lane patterns are
// conflict-free while float4/float2 alignment is preserved (4 | pad).
#define PADX(i) ((i) + ((((i) >> 5)) << 2))

// ---------------------------------------------------------------------------
// Kernel 1: conv1(1->8,k7,s4,p3) -> BN -> ReLU
//           conv2(8->16,k5,s4,p2) -> BN -> ReLU
//           conv3(16->32,k3,s2,p1) -> BN -> ReLU
//           spatial mean + LIF scan -> bit-packed spikes [B][32]
// One block (256 threads) per batch element.
// Weights are read with WAVE-UNIFORM indices -> scalar (SMEM) loads; LDS is
// used only for activations, with padded addressing (no bank conflicts).
// ---------------------------------------------------------------------------
__global__ __launch_bounds__(256) void conv_lif_kernel(
    const float* __restrict__ x,
    const float* __restrict__ w1, const float* __restrict__ b1,
    const float* __restrict__ g1, const float* __restrict__ be1,
    const float* __restrict__ m1, const float* __restrict__ v1,
    const float* __restrict__ w2, const float* __restrict__ b2,
    const float* __restrict__ g2, const float* __restrict__ be2,
    const float* __restrict__ m2, const float* __restrict__ v2,
    const float* __restrict__ w3, const float* __restrict__ b3,
    const float* __restrict__ g3, const float* __restrict__ be3,
    const float* __restrict__ m3, const float* __restrict__ v3,
    float* __restrict__ spatial_out,        // [B][32]
    unsigned int* __restrict__ spk)         // [B][32] bitmask per (b,t)
{
    // logical layouts (before padding):
    //   xs: [8 zeros | 1024 x | 8 zeros]                (window x[4t-3..4t+3] -> idx 4t+5..4t+11)
    //   c1: per ch [2 zeros | 256 data]   idx = pos+2   (conv2 window idx 4p..4p+4)
    //   c2: per ch [1 zero  | 64 data]    idx = pos+1   (conv3 window idx 2p..2p+2)
    __shared__ alignas(16) float xs[1168];          // PADX(1039)=1167
    __shared__ alignas(16) float c1[8 * 292];       // PADX(256)=288, row 292 (16B-aligned rows)
    __shared__ alignas(16) float c2[16 * 76];       // PADX(64)=72,  row 76
    __shared__ alignas(16) float c3[32 * 33];       // +1 pad for LIF column reads

    const int b   = blockIdx.x;
    const int tid = threadIdx.x;

    // ---- zero pads ----
    if (tid < 8) {
        xs[tid] = 0.f;                              // PADX(0..7) = 0..7
        xs[PADX(1032 + tid)] = 0.f;
    } else if (tid >= 32 && tid < 48) {
        int j = tid - 32;                           // c1 front zeros: 8 rows x 2
        c1[(j >> 1) * 292 + (j & 1)] = 0.f;         // PADX(0/1) = 0/1
    } else if (tid >= 64 && tid < 80) {
        c2[(tid - 64) * 76] = 0.f;                  // c2 front zeros
    }

    // ---- stage x (coalesced float4; 4-aligned logical never crosses a pad) ----
    {
        float4 xv = reinterpret_cast<const float4*>(x + (size_t)b * 1024)[tid];
        *reinterpret_cast<float4*>(&xs[PADX(8 + 4 * tid)]) = xv;
    }
    __syncthreads();

    // ---- conv1: thread = output position t (256), all 8 channels ----
    // weights w1[c*7+k]: loop-uniform -> scalar loads
    {
        const int t    = tid;
        const int base = 4 * t + 4;
        float4 xa = *reinterpret_cast<const float4*>(&xs[PADX(base)]);
        float4 xb = *reinterpret_cast<const float4*>(&xs[PADX(base + 4)]);
        float win[7] = {xa.y, xa.z, xa.w, xb.x, xb.y, xb.z, xb.w};
        #pragma unroll
        for (int c = 0; c < 8; c++) {
            float inv = g1[c] * rsqrtf(v1[c] + EPS_BN);
            float bi  = (b1[c] - m1[c]) * inv + be1[c];
            float acc = 0.f;
            #pragma unroll
            for (int k = 0; k < 7; k++) acc = fmaf(w1[c * 7 + k], win[k], acc);
            acc = fmaf(acc, inv, bi);
            c1[c * 292 + PADX(2 + t)] = fmaxf(acc, 0.f);
        }
    }
    __syncthreads();

    // ---- conv2: wave = 4 output channels, lane = position (64) ----
    // window read once per ci, shared across the wave's 4 channels.
    {
        const int p  = tid & 63;
        const int cg = __builtin_amdgcn_readfirstlane((int)(threadIdx.x >> 6)) << 2;  // 0,4,8,12
        float a[4] = {0.f, 0.f, 0.f, 0.f};
        #pragma unroll
        for (int ci = 0; ci < 8; ci++) {
            const float* row = &c1[ci * 292];
            const int basel = 4 * p;
            float4 va = *reinterpret_cast<const float4*>(&row[PADX(basel)]);
            float  v4 = row[PADX(basel + 4)];
            float win[5] = {va.x, va.y, va.z, va.w, v4};
            #pragma unroll
            for (int j = 0; j < 4; j++) {
                const float* wr = &w2[((cg + j) * 8 + ci) * 5];   // uniform -> s_load
                a[j] = fmaf(wr[0], win[0], a[j]);
                a[j] = fmaf(wr[1], win[1], a[j]);
                a[j] = fmaf(wr[2], win[2], a[j]);
                a[j] = fmaf(wr[3], win[3], a[j]);
                a[j] = fmaf(wr[4], win[4], a[j]);
            }
        }
        #pragma unroll
        for (int j = 0; j < 4; j++) {
            int c = cg + j;
            float inv = g2[c] * rsqrtf(v2[c] + EPS_BN);
            float bi  = (b2[c] - m2[c]) * inv + be2[c];
            c2[c * 76 + PADX(1 + p)] = fmaxf(fmaf(a[j], inv, bi), 0.f);
        }
    }
    __syncthreads();

    // ---- conv3: wave = 8 output channels, lanes 0-31 = positions ----
    // (upper lane half duplicates positions; writes predicated to lanes 0-31)
    {
        const int p  = tid & 31;
        const int cg = __builtin_amdgcn_readfirstlane((int)(threadIdx.x >> 6)) << 3;  // 0,8,16,24
        float a[8] = {0.f, 0.f, 0.f, 0.f, 0.f, 0.f, 0.f, 0.f};
        #pragma unroll
        for (int ci = 0; ci < 16; ci++) {
            const float* row = &c2[ci * 76];
            const int basel = 2 * p;
            float2 vab = *reinterpret_cast<const float2*>(&row[PADX(basel)]);
            float  vc  = row[PADX(basel + 2)];
            #pragma unroll
            for (int j = 0; j < 8; j++) {
                const float* wr = &w3[((cg + j) * 16 + ci) * 3];  // uniform -> s_load
                a[j] = fmaf(wr[0], vab.x, a[j]);
                a[j] = fmaf(wr[1], vab.y, a[j]);
                a[j] = fmaf(wr[2], vc,    a[j]);
            }
        }
        if ((tid & 63) < 32) {
            #pragma unroll
            for (int j = 0; j < 8; j++) {
                int c = cg + j;
                float inv = g3[c] * rsqrtf(v3[c] + EPS_BN);
                float bi  = (b3[c] - m3[c]) * inv + be3[c];
                c3[c * 33 + p] = fmaxf(fmaf(a[j], inv, bi), 0.f);
            }
        }
    }
    __syncthreads();

    // ---- spatial mean + LIF scan (lanes 0..31 of wave 0) ----
    if (tid < 32) {
        float s = 0.f;
        #pragma unroll
        for (int t = 0; t < 32; t++) s += c3[tid * 33 + t];
        spatial_out[(size_t)b * 32 + tid] = s * 0.03125f;

        float mem = 0.f;
        #pragma unroll
        for (int t = 0; t < 32; t++) {
            mem = __fadd_rn(__fmul_rn(0.9f, mem), c3[tid * 33 + t]);
            bool spike = mem > 0.5f;
            mem = spike ? 0.f : mem;
            unsigned long long msk = __ballot(spike);
            if (tid == 0) spk[(size_t)b * 32 + t] = (unsigned int)(msk & 0xffffffffull);
        }
    }
}

// ---------------------------------------------------------------------------
// Kernel 2: 32-step LSTM + fused FC head. ONE WAVE (64 threads) per batch;
// lane l owns gate rows l (i/f) and l+64 (g/o). No barriers in the time loop
// (single wave => LDS ops are program-ordered). Binary input projection uses
// wave-uniform SALU mask->float (0x3f800000 * bit) => FMA with SGPR operand.
// ---------------------------------------------------------------------------
__global__ __launch_bounds__(64, 2) void lstm_fc_kernel(
    const unsigned int* __restrict__ spk,   // [B][32]
    const float* __restrict__ w_ih, const float* __restrict__ w_hh,
    const float* __restrict__ b_ih, const float* __restrict__ b_hh,
    const float* __restrict__ fc1w, const float* __restrict__ fc1b,
    const float* __restrict__ fc2w, const float* __restrict__ fc2b,
    const float* __restrict__ fc3w, const float* __restrict__ fc3b,
    const float* __restrict__ spatial_in,   // [B][32]
    float* __restrict__ out0,               // [B][4]
    float* __restrict__ hlast_out)          // [B][32]
{
    const int l  = threadIdx.x;             // 0..63
    const int r0 = l;                       // i (l<32) / f (l>=32)
    const int r1 = l + 64;                  // g (l<32) / o (l>=32)

    float wi0[32], wh0[32], wi1[32], wh1[32];
    #pragma unroll
    for (int q = 0; q < 8; q++) {
        float4 a = reinterpret_cast<const float4*>(w_ih + r0 * 32)[q];
        wi0[4*q+0] = a.x; wi0[4*q+1] = a.y; wi0[4*q+2] = a.z; wi0[4*q+3] = a.w;
        float4 c = reinterpret_cast<const float4*>(w_hh + r0 * 32)[q];
        wh0[4*q+0] = c.x; wh0[4*q+1] = c.y; wh0[4*q+2] = c.z; wh0[4*q+3] = c.w;
        float4 e = reinterpret_cast<const float4*>(w_ih + r1 * 32)[q];
        wi1[4*q+0] = e.x; wi1[4*q+1] = e.y; wi1[4*q+2] = e.z; wi1[4*q+3] = e.w;
        float4 f = reinterpret_cast<const float4*>(w_hh + r1 * 32)[q];
        wh1[4*q+0] = f.x; wh1[4*q+1] = f.y; wh1[4*q+2] = f.z; wh1[4*q+3] = f.w;
    }
    const float bias0 = b_ih[r0] + b_hh[r0];
    const float bias1 = b_ih[r1] + b_hh[r1];
    // act1 = a1m * sigmoid(a1s * x) + a1c :  tanh for l<32, sigmoid for l>=32
    const float a1s = (l < 32) ? 2.f : 1.f;
    const float a1m = (l < 32) ? 2.f : 1.f;
    const float a1c = (l < 32) ? -1.f : 0.f;

    __shared__ alignas(16) float hbuf[32];
    __shared__ alignas(16) float z1b[64];
    __shared__ alignas(16) float z2b[32];

    for (int b = blockIdx.x; b < NB; b += 2048) {
        const unsigned int* mrow = spk + (size_t)b * 32;
        if (l < 32) hbuf[l] = 0.f;
        float cst = 0.f;
        float h = 0.f;

        unsigned int s_cur = mrow[0];
        #pragma unroll 1
        for (int t = 0; t < 32; t++) {
            unsigned int s_nxt = (t < 31) ? mrow[t + 1] : 0u;
            float p0 = bias0, q0 = 0.f;     // two chains per row for ILP
            float p1 = bias1, q1 = 0.f;
            // hidden projection: broadcast LDS reads
            #pragma unroll
            for (int k = 0; k < 8; k++) {
                float4 h4 = reinterpret_cast<const float4*>(hbuf)[k];
                p0 = fmaf(wh0[4*k+0], h4.x, p0); q0 = fmaf(wh0[4*k+1], h4.y, q0);
                p0 = fmaf(wh0[4*k+2], h4.z, p0); q0 = fmaf(wh0[4*k+3], h4.w, q0);
                p1 = fmaf(wh1[4*k+0], h4.x, p1); q1 = fmaf(wh1[4*k+1], h4.y, q1);
                p1 = fmaf(wh1[4*k+2], h4.z, p1); q1 = fmaf(wh1[4*k+3], h4.w, q1);
            }
            // input projection: uniform mask -> float on the SCALAR side
            #pragma unroll
            for (int ff = 0; ff < 32; ff += 2) {
                float xf0 = __uint_as_float(((s_cur >> ff) & 1u) * 0x3f800000u);
                float xf1 = __uint_as_float(((s_cur >> (ff + 1)) & 1u) * 0x3f800000u);
                p0 = fmaf(xf0, wi0[ff], p0);   q0 = fmaf(xf1, wi0[ff + 1], q0);
                p1 = fmaf(xf0, wi1[ff], p1);   q1 = fmaf(xf1, wi1[ff + 1], q1);
            }
            float acc0 = p0 + q0;
            float acc1 = p1 + q1;
            // activations (exp+rcp; saturation-safe)
            float act0 = __builtin_amdgcn_rcpf(1.f + __expf(-acc0));          // sig(i|f)
            float act1 = fmaf(a1m, __builtin_amdgcn_rcpf(1.f + __expf(-a1s * acc1)), a1c);
            float fv = __shfl_xor(act0, 32);   // sigmoid(f) for l<32
            float ov = __shfl_xor(act1, 32);   // sigmoid(o) for l<32
            cst = fmaf(fv, cst, act0 * act1);  // f*c + i*g   (valid l<32)
            float th = fmaf(2.f, __builtin_amdgcn_rcpf(1.f + __expf(-2.f * cst)), -1.f);
            h = ov * th;
            if (l < 32) hbuf[l] = h;           // single wave: program-ordered
            s_cur = s_nxt;
        }

        // ---- FC head (single wave, LDS program-ordered) ----
        if (l < 32) hlast_out[(size_t)b * 32 + l] = h;

        float accA = fc1b[l], accB = 0.f;
        #pragma unroll
        for (int q = 0; q < 8; q++) {
            float4 hv = reinterpret_cast<const float4*>(hbuf)[q];
            float4 wv = reinterpret_cast<const float4*>(fc1w + l * 64)[q];
            accA = fmaf(wv.x, hv.x, accA); accB = fmaf(wv.y, hv.y, accB);
            accA = fmaf(wv.z, hv.z, accA); accB = fmaf(wv.w, hv.w, accB);
        }
        #pragma unroll
        for (int q = 0; q < 8; q++) {
            float4 sv = reinterpret_cast<const float4*>(spatial_in + (size_t)b * 32)[q];
            float4 wv = reinterpret_cast<const float4*>(fc1w + l * 64 + 32)[q];
            accA = fmaf(wv.x, sv.x, accA); accB = fmaf(wv.y, sv.y, accB);
            accA = fmaf(wv.z, sv.z, accA); accB = fmaf(wv.w, sv.w, accB);
        }
        z1b[l] = fmaxf(accA + accB, 0.f);

        if (l < 32) {
            float aA = fc2b[l], aB = 0.f;
            #pragma unroll
            for (int q = 0; q < 16; q++) {
                float4 zv = reinterpret_cast<const float4*>(z1b)[q];
                float4 wv = reinterpret_cast<const float4*>(fc2w + l * 64)[q];
                aA = fmaf(wv.x, zv.x, aA); aB = fmaf(wv.y, zv.y, aB);
                aA = fmaf(wv.z, zv.z, aA); aB = fmaf(wv.w, zv.w, aB);
            }
            z2b[l] = fmaxf(aA + aB, 0.f);
        }
        if (l < 4) {
            float aA = fc3b[l], aB = 0.f;
            #pragma unroll
            for (int q = 0; q < 8; q++) {
                float4 zv = reinterpret_cast<const float4*>(z2b)[q];
                float4 wv = reinterpret_cast<const float4*>(fc3w + l * 32)[q];
                aA = fmaf(wv.x, zv.x, aA); aB = fmaf(wv.y, zv.y, aB);
                aA = fmaf(wv.z, zv.z, aA); aB = fmaf(wv.w, zv.w, aB);
            }
            out0[(size_t)b * 4 + l] = aA + aB;
        }
    }
}

// ---------------------------------------------------------------------------
extern "C" void kernel_launch(void* const* d_in, const int* in_sizes, int n_in,
                              void* d_out, int out_size, void* d_ws, size_t ws_size,
                              hipStream_t stream) {
    const float* x    = (const float*)d_in[0];
    const float* w1   = (const float*)d_in[1];
    const float* b1   = (const float*)d_in[2];
    const float* g1   = (const float*)d_in[3];
    const float* be1  = (const float*)d_in[4];
    const float* m1   = (const float*)d_in[5];
    const float* v1   = (const float*)d_in[6];
    const float* w2   = (const float*)d_in[7];
    const float* b2   = (const float*)d_in[8];
    const float* g2   = (const float*)d_in[9];
    const float* be2  = (const float*)d_in[10];
    const float* m2   = (const float*)d_in[11];
    const float* v2   = (const float*)d_in[12];
    const float* w3   = (const float*)d_in[13];
    const float* b3   = (const float*)d_in[14];
    const float* g3   = (const float*)d_in[15];
    const float* be3  = (const float*)d_in[16];
    const float* m3   = (const float*)d_in[17];
    const float* v3   = (const float*)d_in[18];
    const float* w_ih = (const float*)d_in[19];
    const float* w_hh = (const float*)d_in[20];
    const float* b_ih = (const float*)d_in[21];
    const float* b_hh = (const float*)d_in[22];
    const float* fc1w = (const float*)d_in[23];
    const float* fc1b = (const float*)d_in[24];
    const float* fc2w = (const float*)d_in[25];
    const float* fc2b = (const float*)d_in[26];
    const float* fc3w = (const float*)d_in[27];
    const float* fc3b = (const float*)d_in[28];

    float* out0    = (float*)d_out;                 // [8192][4]
    float* spatial = out0 + (size_t)NB * 4;         // [8192][32]
    float* hlast   = spatial + (size_t)NB * 32;     // [8192][32]
    unsigned int* spk = (unsigned int*)d_ws;        // [8192][32] bitmasks

    hipLaunchKernelGGL(conv_lif_kernel, dim3(NB), dim3(256), 0, stream,
                       x, w1, b1, g1, be1, m1, v1,
                       w2, b2, g2, be2, m2, v2,
                       w3, b3, g3, be3, m3, v3,
                       spatial, spk);

    hipLaunchKernelGGL(lstm_fc_kernel, dim3(2048), dim3(64), 0, stream,
                       spk, w_ih, w_hh, b_ih, b_hh,
                       fc1w, fc1b, fc2w, fc2b, fc3w, fc3b,
                       spatial, out0, hlast);
}

// Round 4
// 151.134 us; speedup vs baseline: 1.8097x; 1.0888x over previous
//
#include <hip/hip_runtime.h>

#define NB 8192
#define EPS_BN 1e-5f

// padded LDS index: +4 floats every 32 => stride-16B lane patterns are
// conflict-free while float4/float2 alignment is preserved (4 | pad).
#define PADX(i) ((i) + ((((i) >> 5)) << 2))

// ---------------------------------------------------------------------------
// Kernel 1: conv1(1->8,k7,s4,p3) -> BN -> ReLU
//           conv2(8->16,k5,s4,p2) -> BN -> ReLU
//           conv3(16->32,k3,s2,p1) -> BN -> ReLU
//           spatial mean + LIF scan -> bit-packed spikes [B][32]
// One block (256 threads) per batch element.
// Weights are read with WAVE-UNIFORM indices -> scalar (SMEM) loads; LDS is
// used only for activations, with padded addressing (no bank conflicts).
// ---------------------------------------------------------------------------
__global__ __launch_bounds__(256) void conv_lif_kernel(
    const float* __restrict__ x,
    const float* __restrict__ w1, const float* __restrict__ b1,
    const float* __restrict__ g1, const float* __restrict__ be1,
    const float* __restrict__ m1, const float* __restrict__ v1,
    const float* __restrict__ w2, const float* __restrict__ b2,
    const float* __restrict__ g2, const float* __restrict__ be2,
    const float* __restrict__ m2, const float* __restrict__ v2,
    const float* __restrict__ w3, const float* __restrict__ b3,
    const float* __restrict__ g3, const float* __restrict__ be3,
    const float* __restrict__ m3, const float* __restrict__ v3,
    float* __restrict__ spatial_out,        // [B][32]
    unsigned int* __restrict__ spk)         // [B][32] bitmask per (b,t)
{
    __shared__ alignas(16) float xs[1168];          // PADX(1039)=1167
    __shared__ alignas(16) float c1[8 * 292];       // PADX(256)=288, row 292
    __shared__ alignas(16) float c2[16 * 76];       // PADX(64)=72,  row 76
    __shared__ alignas(16) float c3[32 * 33];       // +1 pad for LIF column reads

    const int b   = blockIdx.x;
    const int tid = threadIdx.x;

    // ---- zero pads ----
    if (tid < 8) {
        xs[tid] = 0.f;
        xs[PADX(1032 + tid)] = 0.f;
    } else if (tid >= 32 && tid < 48) {
        int j = tid - 32;
        c1[(j >> 1) * 292 + (j & 1)] = 0.f;
    } else if (tid >= 64 && tid < 80) {
        c2[(tid - 64) * 76] = 0.f;
    }

    // ---- stage x (coalesced float4) ----
    {
        float4 xv = reinterpret_cast<const float4*>(x + (size_t)b * 1024)[tid];
        *reinterpret_cast<float4*>(&xs[PADX(8 + 4 * tid)]) = xv;
    }
    __syncthreads();

    // ---- conv1: thread = output position t (256), all 8 channels ----
    {
        const int t    = tid;
        const int base = 4 * t + 4;
        float4 xa = *reinterpret_cast<const float4*>(&xs[PADX(base)]);
        float4 xb = *reinterpret_cast<const float4*>(&xs[PADX(base + 4)]);
        float win[7] = {xa.y, xa.z, xa.w, xb.x, xb.y, xb.z, xb.w};
        #pragma unroll
        for (int c = 0; c < 8; c++) {
            float inv = g1[c] * rsqrtf(v1[c] + EPS_BN);
            float bi  = (b1[c] - m1[c]) * inv + be1[c];
            float acc = 0.f;
            #pragma unroll
            for (int k = 0; k < 7; k++) acc = fmaf(w1[c * 7 + k], win[k], acc);
            acc = fmaf(acc, inv, bi);
            c1[c * 292 + PADX(2 + t)] = fmaxf(acc, 0.f);
        }
    }
    __syncthreads();

    // ---- conv2: wave = 4 output channels, lane = position (64) ----
    {
        const int p  = tid & 63;
        const int cg = __builtin_amdgcn_readfirstlane((int)(threadIdx.x >> 6)) << 2;
        float a[4] = {0.f, 0.f, 0.f, 0.f};
        #pragma unroll
        for (int ci = 0; ci < 8; ci++) {
            const float* row = &c1[ci * 292];
            const int basel = 4 * p;
            float4 va = *reinterpret_cast<const float4*>(&row[PADX(basel)]);
            float  v4 = row[PADX(basel + 4)];
            float win[5] = {va.x, va.y, va.z, va.w, v4};
            #pragma unroll
            for (int j = 0; j < 4; j++) {
                const float* wr = &w2[((cg + j) * 8 + ci) * 5];   // uniform -> s_load
                a[j] = fmaf(wr[0], win[0], a[j]);
                a[j] = fmaf(wr[1], win[1], a[j]);
                a[j] = fmaf(wr[2], win[2], a[j]);
                a[j] = fmaf(wr[3], win[3], a[j]);
                a[j] = fmaf(wr[4], win[4], a[j]);
            }
        }
        #pragma unroll
        for (int j = 0; j < 4; j++) {
            int c = cg + j;
            float inv = g2[c] * rsqrtf(v2[c] + EPS_BN);
            float bi  = (b2[c] - m2[c]) * inv + be2[c];
            c2[c * 76 + PADX(1 + p)] = fmaxf(fmaf(a[j], inv, bi), 0.f);
        }
    }
    __syncthreads();

    // ---- conv3: wave = 8 output channels, lanes 0-31 = positions ----
    {
        const int p  = tid & 31;
        const int cg = __builtin_amdgcn_readfirstlane((int)(threadIdx.x >> 6)) << 3;
        float a[8] = {0.f, 0.f, 0.f, 0.f, 0.f, 0.f, 0.f, 0.f};
        #pragma unroll
        for (int ci = 0; ci < 16; ci++) {
            const float* row = &c2[ci * 76];
            const int basel = 2 * p;
            float2 vab = *reinterpret_cast<const float2*>(&row[PADX(basel)]);
            float  vc  = row[PADX(basel + 2)];
            #pragma unroll
            for (int j = 0; j < 8; j++) {
                const float* wr = &w3[((cg + j) * 16 + ci) * 3];  // uniform -> s_load
                a[j] = fmaf(wr[0], vab.x, a[j]);
                a[j] = fmaf(wr[1], vab.y, a[j]);
                a[j] = fmaf(wr[2], vc,    a[j]);
            }
        }
        if ((tid & 63) < 32) {
            #pragma unroll
            for (int j = 0; j < 8; j++) {
                int c = cg + j;
                float inv = g3[c] * rsqrtf(v3[c] + EPS_BN);
                float bi  = (b3[c] - m3[c]) * inv + be3[c];
                c3[c * 33 + p] = fmaxf(fmaf(a[j], inv, bi), 0.f);
            }
        }
    }
    __syncthreads();

    // ---- spatial mean + LIF scan (lanes 0..31 of wave 0) ----
    if (tid < 32) {
        float s = 0.f;
        #pragma unroll
        for (int t = 0; t < 32; t++) s += c3[tid * 33 + t];
        spatial_out[(size_t)b * 32 + tid] = s * 0.03125f;

        float mem = 0.f;
        #pragma unroll
        for (int t = 0; t < 32; t++) {
            mem = __fadd_rn(__fmul_rn(0.9f, mem), c3[tid * 33 + t]);
            bool spike = mem > 0.5f;
            mem = spike ? 0.f : mem;
            unsigned long long msk = __ballot(spike);
            if (tid == 0) spk[(size_t)b * 32 + t] = (unsigned int)(msk & 0xffffffffull);
        }
    }
}

// ---------------------------------------------------------------------------
// Kernel 2: 32-step LSTM + fused FC head. ONE WAVE (64 threads) per batch
// element, one block per batch (grid = NB). launch_bounds(64,3) caps VGPR at
// ~170 so the 128 weight VGPRs stay RESIDENT across the t-loop (round-3 regalloc
// spilled them at 124 VGPRs and re-loaded per iteration). Spike mask forced to
// SALU via readfirstlane (wave-uniform) -> mask math on scalar pipe, FMAs take
// the mask float as the single SGPR operand.
// ---------------------------------------------------------------------------
__global__ __launch_bounds__(64, 3) void lstm_fc_kernel(
    const unsigned int* __restrict__ spk,   // [B][32]
    const float* __restrict__ w_ih, const float* __restrict__ w_hh,
    const float* __restrict__ b_ih, const float* __restrict__ b_hh,
    const float* __restrict__ fc1w, const float* __restrict__ fc1b,
    const float* __restrict__ fc2w, const float* __restrict__ fc2b,
    const float* __restrict__ fc3w, const float* __restrict__ fc3b,
    const float* __restrict__ spatial_in,   // [B][32]
    float* __restrict__ out0,               // [B][4]
    float* __restrict__ hlast_out)          // [B][32]
{
    const int l  = threadIdx.x;             // 0..63
    const int r0 = l;                       // i (l<32) / f (l>=32)
    const int r1 = l + 64;                  // g (l<32) / o (l>=32)
    const int b  = blockIdx.x;

    float wi0[32], wh0[32], wi1[32], wh1[32];
    #pragma unroll
    for (int q = 0; q < 8; q++) {
        float4 a = reinterpret_cast<const float4*>(w_ih + r0 * 32)[q];
        wi0[4*q+0] = a.x; wi0[4*q+1] = a.y; wi0[4*q+2] = a.z; wi0[4*q+3] = a.w;
        float4 c = reinterpret_cast<const float4*>(w_hh + r0 * 32)[q];
        wh0[4*q+0] = c.x; wh0[4*q+1] = c.y; wh0[4*q+2] = c.z; wh0[4*q+3] = c.w;
        float4 e = reinterpret_cast<const float4*>(w_ih + r1 * 32)[q];
        wi1[4*q+0] = e.x; wi1[4*q+1] = e.y; wi1[4*q+2] = e.z; wi1[4*q+3] = e.w;
        float4 f = reinterpret_cast<const float4*>(w_hh + r1 * 32)[q];
        wh1[4*q+0] = f.x; wh1[4*q+1] = f.y; wh1[4*q+2] = f.z; wh1[4*q+3] = f.w;
    }
    const float bias0 = b_ih[r0] + b_hh[r0];
    const float bias1 = b_ih[r1] + b_hh[r1];
    // act1 = a1m * sigmoid(a1s * x) + a1c :  tanh for l<32, sigmoid for l>=32
    const float a1s = (l < 32) ? 2.f : 1.f;
    const float a1m = (l < 32) ? 2.f : 1.f;
    const float a1c = (l < 32) ? -1.f : 0.f;

    __shared__ alignas(16) float hbuf[32];
    __shared__ alignas(16) float z1b[64];
    __shared__ alignas(16) float z2b[32];

    const unsigned int* mrow = spk + (size_t)b * 32;
    if (l < 32) hbuf[l] = 0.f;
    float cst = 0.f;
    float h = 0.f;

    unsigned int s_cur = (unsigned int)__builtin_amdgcn_readfirstlane((int)mrow[0]);
    #pragma unroll 1
    for (int t = 0; t < 32; t++) {
        unsigned int s_nxt = (t < 31)
            ? (unsigned int)__builtin_amdgcn_readfirstlane((int)mrow[t + 1]) : 0u;
        float p0 = bias0, q0 = 0.f;     // two chains per row for ILP
        float p1 = bias1, q1 = 0.f;
        // hidden projection: broadcast LDS reads
        #pragma unroll
        for (int k = 0; k < 8; k++) {
            float4 h4 = reinterpret_cast<const float4*>(hbuf)[k];
            p0 = fmaf(wh0[4*k+0], h4.x, p0); q0 = fmaf(wh0[4*k+1], h4.y, q0);
            p0 = fmaf(wh0[4*k+2], h4.z, p0); q0 = fmaf(wh0[4*k+3], h4.w, q0);
            p1 = fmaf(wh1[4*k+0], h4.x, p1); q1 = fmaf(wh1[4*k+1], h4.y, q1);
            p1 = fmaf(wh1[4*k+2], h4.z, p1); q1 = fmaf(wh1[4*k+3], h4.w, q1);
        }
        // input projection: uniform mask -> float on the SCALAR side
        #pragma unroll
        for (int ff = 0; ff < 32; ff += 2) {
            float xf0 = __uint_as_float(((s_cur >> ff) & 1u) * 0x3f800000u);
            float xf1 = __uint_as_float(((s_cur >> (ff + 1)) & 1u) * 0x3f800000u);
            p0 = fmaf(xf0, wi0[ff], p0);   q0 = fmaf(xf1, wi0[ff + 1], q0);
            p1 = fmaf(xf0, wi1[ff], p1);   q1 = fmaf(xf1, wi1[ff + 1], q1);
        }
        float acc0 = p0 + q0;
        float acc1 = p1 + q1;
        // activations (exp+rcp; saturation-safe)
        float act0 = __builtin_amdgcn_rcpf(1.f + __expf(-acc0));          // sig(i|f)
        float act1 = fmaf(a1m, __builtin_amdgcn_rcpf(1.f + __expf(-a1s * acc1)), a1c);
        float fv = __shfl_xor(act0, 32);   // sigmoid(f) for l<32
        float ov = __shfl_xor(act1, 32);   // sigmoid(o) for l<32
        cst = fmaf(fv, cst, act0 * act1);  // f*c + i*g   (valid l<32)
        float th = fmaf(2.f, __builtin_amdgcn_rcpf(1.f + __expf(-2.f * cst)), -1.f);
        h = ov * th;
        if (l < 32) hbuf[l] = h;           // single wave: program-ordered
        s_cur = s_nxt;
    }

    // ---- FC head (single wave, LDS program-ordered) ----
    if (l < 32) hlast_out[(size_t)b * 32 + l] = h;

    float accA = fc1b[l], accB = 0.f;
    #pragma unroll
    for (int q = 0; q < 8; q++) {
        float4 hv = reinterpret_cast<const float4*>(hbuf)[q];
        float4 wv = reinterpret_cast<const float4*>(fc1w + l * 64)[q];
        accA = fmaf(wv.x, hv.x, accA); accB = fmaf(wv.y, hv.y, accB);
        accA = fmaf(wv.z, hv.z, accA); accB = fmaf(wv.w, hv.w, accB);
    }
    #pragma unroll
    for (int q = 0; q < 8; q++) {
        float4 sv = reinterpret_cast<const float4*>(spatial_in + (size_t)b * 32)[q];
        float4 wv = reinterpret_cast<const float4*>(fc1w + l * 64 + 32)[q];
        accA = fmaf(wv.x, sv.x, accA); accB = fmaf(wv.y, sv.y, accB);
        accA = fmaf(wv.z, sv.z, accA); accB = fmaf(wv.w, sv.w, accB);
    }
    z1b[l] = fmaxf(accA + accB, 0.f);

    if (l < 32) {
        float aA = fc2b[l], aB = 0.f;
        #pragma unroll
        for (int q = 0; q < 16; q++) {
            float4 zv = reinterpret_cast<const float4*>(z1b)[q];
            float4 wv = reinterpret_cast<const float4*>(fc2w + l * 64)[q];
            aA = fmaf(wv.x, zv.x, aA); aB = fmaf(wv.y, zv.y, aB);
            aA = fmaf(wv.z, zv.z, aA); aB = fmaf(wv.w, zv.w, aB);
        }
        z2b[l] = fmaxf(aA + aB, 0.f);
    }
    if (l < 4) {
        float aA = fc3b[l], aB = 0.f;
        #pragma unroll
        for (int q = 0; q < 8; q++) {
            float4 zv = reinterpret_cast<const float4*>(z2b)[q];
            float4 wv = reinterpret_cast<const float4*>(fc3w + l * 32)[q];
            aA = fmaf(wv.x, zv.x, aA); aB = fmaf(wv.y, zv.y, aB);
            aA = fmaf(wv.z, zv.z, aA); aB = fmaf(wv.w, zv.w, aB);
        }
        out0[(size_t)b * 4 + l] = aA + aB;
    }
}

// ---------------------------------------------------------------------------
extern "C" void kernel_launch(void* const* d_in, const int* in_sizes, int n_in,
                              void* d_out, int out_size, void* d_ws, size_t ws_size,
                              hipStream_t stream) {
    const float* x    = (const float*)d_in[0];
    const float* w1   = (const float*)d_in[1];
    const float* b1   = (const float*)d_in[2];
    const float* g1   = (const float*)d_in[3];
    const float* be1  = (const float*)d_in[4];
    const float* m1   = (const float*)d_in[5];
    const float* v1   = (const float*)d_in[6];
    const float* w2   = (const float*)d_in[7];
    const float* b2   = (const float*)d_in[8];
    const float* g2   = (const float*)d_in[9];
    const float* be2  = (const float*)d_in[10];
    const float* m2   = (const float*)d_in[11];
    const float* v2   = (const float*)d_in[12];
    const float* w3   = (const float*)d_in[13];
    const float* b3   = (const float*)d_in[14];
    const float* g3   = (const float*)d_in[15];
    const float* be3  = (const float*)d_in[16];
    const float* m3   = (const float*)d_in[17];
    const float* v3   = (const float*)d_in[18];
    const float* w_ih = (const float*)d_in[19];
    const float* w_hh = (const float*)d_in[20];
    const float* b_ih = (const float*)d_in[21];
    const float* b_hh = (const float*)d_in[22];
    const float* fc1w = (const float*)d_in[23];
    const float* fc1b = (const float*)d_in[24];
    const float* fc2w = (const float*)d_in[25];
    const float* fc2b = (const float*)d_in[26];
    const float* fc3w = (const float*)d_in[27];
    const float* fc3b = (const float*)d_in[28];

    float* out0    = (float*)d_out;                 // [8192][4]
    float* spatial = out0 + (size_t)NB * 4;         // [8192][32]
    float* hlast   = spatial + (size_t)NB * 32;     // [8192][32]
    unsigned int* spk = (unsigned int*)d_ws;        // [8192][32] bitmasks

    hipLaunchKernelGGL(conv_lif_kernel, dim3(NB), dim3(256), 0, stream,
                       x, w1, b1, g1, be1, m1, v1,
                       w2, b2, g2, be2, m2, v2,
                       w3, b3, g3, be3, m3, v3,
                       spatial, spk);

    hipLaunchKernelGGL(lstm_fc_kernel, dim3(NB), dim3(64), 0, stream,
                       spk, w_ih, w_hh, b_ih, b_hh,
                       fc1w, fc1b, fc2w, fc2b, fc3w, fc3b,
                       spatial, out0, hlast);
}

// Round 5
// 89.520 us; speedup vs baseline: 3.0553x; 1.6883x over previous
//
#include <hip/hip_runtime.h>

#define NB 8192
#define EPS_BN 1e-5f

// padded LDS index: +4 floats every 32 => stride-16B lane patterns are
// conflict-free while float4/float2 alignment is preserved (4 | pad).
#define PADX(i) ((i) + ((((i) >> 5)) << 2))

using bf16x8 = __attribute__((ext_vector_type(8))) __bf16;
using bf16x4 = __attribute__((ext_vector_type(4))) __bf16;
using f32x4  = __attribute__((ext_vector_type(4))) float;

// ---------------------------------------------------------------------------
// Kernel 1: conv stack + LIF (UNCHANGED from round 4)
// ---------------------------------------------------------------------------
__global__ __launch_bounds__(256) void conv_lif_kernel(
    const float* __restrict__ x,
    const float* __restrict__ w1, const float* __restrict__ b1,
    const float* __restrict__ g1, const float* __restrict__ be1,
    const float* __restrict__ m1, const float* __restrict__ v1,
    const float* __restrict__ w2, const float* __restrict__ b2,
    const float* __restrict__ g2, const float* __restrict__ be2,
    const float* __restrict__ m2, const float* __restrict__ v2,
    const float* __restrict__ w3, const float* __restrict__ b3,
    const float* __restrict__ g3, const float* __restrict__ be3,
    const float* __restrict__ m3, const float* __restrict__ v3,
    float* __restrict__ spatial_out,        // [B][32]
    unsigned int* __restrict__ spk)         // [B][32] bitmask per (b,t)
{
    __shared__ alignas(16) float xs[1168];
    __shared__ alignas(16) float c1[8 * 292];
    __shared__ alignas(16) float c2[16 * 76];
    __shared__ alignas(16) float c3[32 * 33];

    const int b   = blockIdx.x;
    const int tid = threadIdx.x;

    if (tid < 8) {
        xs[tid] = 0.f;
        xs[PADX(1032 + tid)] = 0.f;
    } else if (tid >= 32 && tid < 48) {
        int j = tid - 32;
        c1[(j >> 1) * 292 + (j & 1)] = 0.f;
    } else if (tid >= 64 && tid < 80) {
        c2[(tid - 64) * 76] = 0.f;
    }

    {
        float4 xv = reinterpret_cast<const float4*>(x + (size_t)b * 1024)[tid];
        *reinterpret_cast<float4*>(&xs[PADX(8 + 4 * tid)]) = xv;
    }
    __syncthreads();

    {
        const int t    = tid;
        const int base = 4 * t + 4;
        float4 xa = *reinterpret_cast<const float4*>(&xs[PADX(base)]);
        float4 xb = *reinterpret_cast<const float4*>(&xs[PADX(base + 4)]);
        float win[7] = {xa.y, xa.z, xa.w, xb.x, xb.y, xb.z, xb.w};
        #pragma unroll
        for (int c = 0; c < 8; c++) {
            float inv = g1[c] * rsqrtf(v1[c] + EPS_BN);
            float bi  = (b1[c] - m1[c]) * inv + be1[c];
            float acc = 0.f;
            #pragma unroll
            for (int k = 0; k < 7; k++) acc = fmaf(w1[c * 7 + k], win[k], acc);
            acc = fmaf(acc, inv, bi);
            c1[c * 292 + PADX(2 + t)] = fmaxf(acc, 0.f);
        }
    }
    __syncthreads();

    {
        const int p  = tid & 63;
        const int cg = __builtin_amdgcn_readfirstlane((int)(threadIdx.x >> 6)) << 2;
        float a[4] = {0.f, 0.f, 0.f, 0.f};
        #pragma unroll
        for (int ci = 0; ci < 8; ci++) {
            const float* row = &c1[ci * 292];
            const int basel = 4 * p;
            float4 va = *reinterpret_cast<const float4*>(&row[PADX(basel)]);
            float  v4 = row[PADX(basel + 4)];
            float win[5] = {va.x, va.y, va.z, va.w, v4};
            #pragma unroll
            for (int j = 0; j < 4; j++) {
                const float* wr = &w2[((cg + j) * 8 + ci) * 5];
                a[j] = fmaf(wr[0], win[0], a[j]);
                a[j] = fmaf(wr[1], win[1], a[j]);
                a[j] = fmaf(wr[2], win[2], a[j]);
                a[j] = fmaf(wr[3], win[3], a[j]);
                a[j] = fmaf(wr[4], win[4], a[j]);
            }
        }
        #pragma unroll
        for (int j = 0; j < 4; j++) {
            int c = cg + j;
            float inv = g2[c] * rsqrtf(v2[c] + EPS_BN);
            float bi  = (b2[c] - m2[c]) * inv + be2[c];
            c2[c * 76 + PADX(1 + p)] = fmaxf(fmaf(a[j], inv, bi), 0.f);
        }
    }
    __syncthreads();

    {
        const int p  = tid & 31;
        const int cg = __builtin_amdgcn_readfirstlane((int)(threadIdx.x >> 6)) << 3;
        float a[8] = {0.f, 0.f, 0.f, 0.f, 0.f, 0.f, 0.f, 0.f};
        #pragma unroll
        for (int ci = 0; ci < 16; ci++) {
            const float* row = &c2[ci * 76];
            const int basel = 2 * p;
            float2 vab = *reinterpret_cast<const float2*>(&row[PADX(basel)]);
            float  vc  = row[PADX(basel + 2)];
            #pragma unroll
            for (int j = 0; j < 8; j++) {
                const float* wr = &w3[((cg + j) * 16 + ci) * 3];
                a[j] = fmaf(wr[0], vab.x, a[j]);
                a[j] = fmaf(wr[1], vab.y, a[j]);
                a[j] = fmaf(wr[2], vc,    a[j]);
            }
        }
        if ((tid & 63) < 32) {
            #pragma unroll
            for (int j = 0; j < 8; j++) {
                int c = cg + j;
                float inv = g3[c] * rsqrtf(v3[c] + EPS_BN);
                float bi  = (b3[c] - m3[c]) * inv + be3[c];
                c3[c * 33 + p] = fmaxf(fmaf(a[j], inv, bi), 0.f);
            }
        }
    }
    __syncthreads();

    if (tid < 32) {
        float s = 0.f;
        #pragma unroll
        for (int t = 0; t < 32; t++) s += c3[tid * 33 + t];
        spatial_out[(size_t)b * 32 + tid] = s * 0.03125f;

        float mem = 0.f;
        #pragma unroll
        for (int t = 0; t < 32; t++) {
            mem = __fadd_rn(__fmul_rn(0.9f, mem), c3[tid * 33 + t]);
            bool spike = mem > 0.5f;
            mem = spike ? 0.f : mem;
            unsigned long long msk = __ballot(spike);
            if (tid == 0) spk[(size_t)b * 32 + t] = (unsigned int)(msk & 0xffffffffull);
        }
    }
}

// ---------------------------------------------------------------------------
// Kernel 2 (rewritten): MFMA-batched LSTM + FC head.
// One 64-thread block = one wave = 16 batch elements.
// Swapped-operand GEMM per step:  D[gate][batch] = Wcat * actT
//   mfma_f32_16x16x32_bf16 operand mapping (CDNA std):
//     A (M=16 x K=32): lane holds A[l&15][8*(l>>4)+i]       (X = weights)
//     B (K=32 x N=16): lane holds B[8*(l>>4)+i][l&15]       (Y = activations)
//     D (M=16 x N=16): lane holds D[4*(l>>4)+reg][l&15]     (m89-verified)
// => lane owns batch (l&15), gate-channels {4q+j, 16+4q+j}, cell update is
//    lane-local; h redistribution = 2 ds_write_b64 + 1 ds_read_b128 / step.
// Weights bf16 (rounded once), h bf16 (per step), accumulate fp32.
// ---------------------------------------------------------------------------
__device__ inline float sigm(float x) {
    return __builtin_amdgcn_rcpf(1.f + __expf(-x));
}
__device__ inline float tanh_(float x) {
    return fmaf(2.f, __builtin_amdgcn_rcpf(1.f + __expf(-2.f * x)), -1.f);
}
__device__ inline bf16x8 ldfrag(const float* __restrict__ p) {
    bf16x8 r;
    #pragma unroll
    for (int i = 0; i < 8; i++) r[i] = (__bf16)p[i];
    return r;
}

__global__ __launch_bounds__(64, 2) void lstm_fc_mfma_kernel(
    const unsigned int* __restrict__ spk,   // [B][32]
    const float* __restrict__ w_ih, const float* __restrict__ w_hh,
    const float* __restrict__ b_ih, const float* __restrict__ b_hh,
    const float* __restrict__ fc1w, const float* __restrict__ fc1b,
    const float* __restrict__ fc2w, const float* __restrict__ fc2b,
    const float* __restrict__ fc3w, const float* __restrict__ fc3b,
    const float* __restrict__ spatial_in,   // [B][32]
    float* __restrict__ out0,               // [B][4]
    float* __restrict__ hlast_out)          // [B][32]
{
    const int l    = threadIdx.x;
    const int row  = l & 15;                // batch-within-tile (and X gate-row)
    const int q    = l >> 4;                // k-group 0..3
    const int base = blockIdx.x * 16;

    __shared__ unsigned int mlds[512];      // [t][16] spike masks
    __shared__ __bf16 hlds[640];            // [16][40]  (stride 40 bf16 = 80B)
    __shared__ __bf16 zlds[1152];           // [16][72]  (stride 72 bf16 = 144B)

    // stage masks (coalesced) + zero h   (single wave: program-ordered LDS)
    for (int i = l; i < 512; i += 64) {
        int j = i >> 5, t = i & 31;
        mlds[t * 16 + j] = spk[(size_t)(base + j) * 32 + t];
    }
    for (int i = l; i < 640; i += 64) hlds[i] = (__bf16)0.f;

    // ---- resident weight fragments (bf16) + bias C-in fragments (f32) ----
    bf16x8 wih[8], whh[8];
    f32x4  bfr[8];
    #pragma unroll
    for (int T = 0; T < 8; T++) {
        wih[T] = ldfrag(w_ih + (size_t)(16 * T + row) * 32 + 8 * q);
        whh[T] = ldfrag(w_hh + (size_t)(16 * T + row) * 32 + 8 * q);
        const float* ba = b_ih + 16 * T + 4 * q;
        const float* bb = b_hh + 16 * T + 4 * q;
        f32x4 bf;
        #pragma unroll
        for (int i = 0; i < 4; i++) bf[i] = ba[i] + bb[i];
        bfr[T] = bf;
    }

    float cst[8];
    float hq[8];
    #pragma unroll
    for (int i = 0; i < 8; i++) { cst[i] = 0.f; hq[i] = 0.f; }

    // ---- 32-step scan ----
    #pragma unroll 1
    for (int t = 0; t < 32; t++) {
        // A1: spike fragment (exact 0/1 bf16) from bitmask byte
        unsigned int m  = mlds[t * 16 + row];
        unsigned int by = (m >> (q * 8)) & 0xFFu;
        union { bf16x8 v; unsigned int u[4]; } a1;
        a1.u[0] = ((by & 1u)        * 0x3F80u) | (((by >> 1) & 1u) * 0x3F800000u);
        a1.u[1] = (((by >> 2) & 1u) * 0x3F80u) | (((by >> 3) & 1u) * 0x3F800000u);
        a1.u[2] = (((by >> 4) & 1u) * 0x3F80u) | (((by >> 5) & 1u) * 0x3F800000u);
        a1.u[3] = (((by >> 6) & 1u) * 0x3F80u) | (((by >> 7) & 1u) * 0x3F800000u);
        // A2: h fragment
        bf16x8 a2 = *reinterpret_cast<bf16x8*>(&hlds[row * 40 + q * 8]);

        f32x4 acc[8];
        #pragma unroll
        for (int T = 0; T < 8; T++) {
            acc[T] = __builtin_amdgcn_mfma_f32_16x16x32_bf16(wih[T], a1.v, bfr[T], 0, 0, 0);
            acc[T] = __builtin_amdgcn_mfma_f32_16x16x32_bf16(whh[T], a2,   acc[T], 0, 0, 0);
        }

        // activations + lane-local cell update
        // tiles: 0,1 = i | 2,3 = f | 4,5 = g | 6,7 = o ; even tile -> ch 4q+j, odd -> 16+4q+j
        #pragma unroll
        for (int j = 0; j < 4; j++) {
            float iv = sigm(acc[0][j]);
            float fv = sigm(acc[2][j]);
            float gv = tanh_(acc[4][j]);
            float ov = sigm(acc[6][j]);
            cst[j] = fmaf(fv, cst[j], iv * gv);
            hq[j]  = ov * tanh_(cst[j]);
            float iv2 = sigm(acc[1][j]);
            float fv2 = sigm(acc[3][j]);
            float gv2 = tanh_(acc[5][j]);
            float ov2 = sigm(acc[7][j]);
            cst[4 + j] = fmaf(fv2, cst[4 + j], iv2 * gv2);
            hq[4 + j]  = ov2 * tanh_(cst[4 + j]);
        }

        // write h back (bf16) for next step's A2
        bf16x4 hv0, hv1;
        #pragma unroll
        for (int j = 0; j < 4; j++) { hv0[j] = (__bf16)hq[j]; hv1[j] = (__bf16)hq[4 + j]; }
        *reinterpret_cast<bf16x4*>(&hlds[row * 40 + 4 * q])      = hv0;
        *reinterpret_cast<bf16x4*>(&hlds[row * 40 + 16 + 4 * q]) = hv1;
    }

    // ---- h_last output (fp32, from registers) ----
    {
        f32x4 lo, hi;
        #pragma unroll
        for (int j = 0; j < 4; j++) { lo[j] = hq[j]; hi[j] = hq[4 + j]; }
        *reinterpret_cast<f32x4*>(hlast_out + (size_t)(base + row) * 32 + 4 * q)      = lo;
        *reinterpret_cast<f32x4*>(hlast_out + (size_t)(base + row) * 32 + 16 + 4 * q) = hi;
    }

    // ---- FC head (swapped MFMA) ----
    bf16x8 hf = *reinterpret_cast<bf16x8*>(&hlds[row * 40 + q * 8]);   // combined k<32
    bf16x8 spf;                                                        // combined k>=32
    {
        const float* sp = spatial_in + (size_t)(base + row) * 32 + 8 * q;
        #pragma unroll
        for (int i = 0; i < 8; i++) spf[i] = (__bf16)sp[i];
    }

    // fc1: 64 outs = 4 tiles, K=64 = 2 slices
    #pragma unroll
    for (int T = 0; T < 4; T++) {
        bf16x8 x0 = ldfrag(fc1w + (size_t)(16 * T + row) * 64 + 8 * q);
        bf16x8 x1 = ldfrag(fc1w + (size_t)(16 * T + row) * 64 + 32 + 8 * q);
        f32x4 c;
        #pragma unroll
        for (int i = 0; i < 4; i++) c[i] = fc1b[16 * T + 4 * q + i];
        f32x4 a = __builtin_amdgcn_mfma_f32_16x16x32_bf16(x0, hf,  c, 0, 0, 0);
        a       = __builtin_amdgcn_mfma_f32_16x16x32_bf16(x1, spf, a, 0, 0, 0);
        bf16x4 zv;
        #pragma unroll
        for (int i = 0; i < 4; i++) zv[i] = (__bf16)fmaxf(a[i], 0.f);
        *reinterpret_cast<bf16x4*>(&zlds[row * 72 + 16 * T + 4 * q]) = zv;
    }
    bf16x8 z1f0 = *reinterpret_cast<bf16x8*>(&zlds[row * 72 + 8 * q]);
    bf16x8 z1f1 = *reinterpret_cast<bf16x8*>(&zlds[row * 72 + 32 + 8 * q]);

    // fc2: 32 outs = 2 tiles, K=64 = 2 slices ; result stored into hlds slots
    #pragma unroll
    for (int T = 0; T < 2; T++) {
        bf16x8 x0 = ldfrag(fc2w + (size_t)(16 * T + row) * 64 + 8 * q);
        bf16x8 x1 = ldfrag(fc2w + (size_t)(16 * T + row) * 64 + 32 + 8 * q);
        f32x4 c;
        #pragma unroll
        for (int i = 0; i < 4; i++) c[i] = fc2b[16 * T + 4 * q + i];
        f32x4 a = __builtin_amdgcn_mfma_f32_16x16x32_bf16(x0, z1f0, c, 0, 0, 0);
        a       = __builtin_amdgcn_mfma_f32_16x16x32_bf16(x1, z1f1, a, 0, 0, 0);
        bf16x4 zv;
        #pragma unroll
        for (int i = 0; i < 4; i++) zv[i] = (__bf16)fmaxf(a[i], 0.f);
        *reinterpret_cast<bf16x4*>(&hlds[row * 40 + 16 * T + 4 * q]) = zv;
    }
    bf16x8 z2f = *reinterpret_cast<bf16x8*>(&hlds[row * 40 + 8 * q]);

    // fc3: 4 outs (rows 0-3 of a padded 16-row tile), K=32
    {
        bf16x8 x3 = ldfrag(fc3w + (size_t)(row & 3) * 32 + 8 * q);  // clamp: rows>=4 garbage, discarded
        f32x4 c;
        #pragma unroll
        for (int i = 0; i < 4; i++) c[i] = fc3b[i];
        f32x4 o = __builtin_amdgcn_mfma_f32_16x16x32_bf16(x3, z2f, c, 0, 0, 0);
        if (l < 16)
            *reinterpret_cast<f32x4*>(out0 + (size_t)(base + row) * 4) = o;
    }
}

// ---------------------------------------------------------------------------
extern "C" void kernel_launch(void* const* d_in, const int* in_sizes, int n_in,
                              void* d_out, int out_size, void* d_ws, size_t ws_size,
                              hipStream_t stream) {
    const float* x    = (const float*)d_in[0];
    const float* w1   = (const float*)d_in[1];
    const float* b1   = (const float*)d_in[2];
    const float* g1   = (const float*)d_in[3];
    const float* be1  = (const float*)d_in[4];
    const float* m1   = (const float*)d_in[5];
    const float* v1   = (const float*)d_in[6];
    const float* w2   = (const float*)d_in[7];
    const float* b2   = (const float*)d_in[8];
    const float* g2   = (const float*)d_in[9];
    const float* be2  = (const float*)d_in[10];
    const float* m2   = (const float*)d_in[11];
    const float* v2   = (const float*)d_in[12];
    const float* w3   = (const float*)d_in[13];
    const float* b3   = (const float*)d_in[14];
    const float* g3   = (const float*)d_in[15];
    const float* be3  = (const float*)d_in[16];
    const float* m3   = (const float*)d_in[17];
    const float* v3   = (const float*)d_in[18];
    const float* w_ih = (const float*)d_in[19];
    const float* w_hh = (const float*)d_in[20];
    const float* b_ih = (const float*)d_in[21];
    const float* b_hh = (const float*)d_in[22];
    const float* fc1w = (const float*)d_in[23];
    const float* fc1b = (const float*)d_in[24];
    const float* fc2w = (const float*)d_in[25];
    const float* fc2b = (const float*)d_in[26];
    const float* fc3w = (const float*)d_in[27];
    const float* fc3b = (const float*)d_in[28];

    float* out0    = (float*)d_out;                 // [8192][4]
    float* spatial = out0 + (size_t)NB * 4;         // [8192][32]
    float* hlast   = spatial + (size_t)NB * 32;     // [8192][32]
    unsigned int* spk = (unsigned int*)d_ws;        // [8192][32] bitmasks

    hipLaunchKernelGGL(conv_lif_kernel, dim3(NB), dim3(256), 0, stream,
                       x, w1, b1, g1, be1, m1, v1,
                       w2, b2, g2, be2, m2, v2,
                       w3, b3, g3, be3, m3, v3,
                       spatial, spk);

    hipLaunchKernelGGL(lstm_fc_mfma_kernel, dim3(NB / 16), dim3(64), 0, stream,
                       spk, w_ih, w_hh, b_ih, b_hh,
                       fc1w, fc1b, fc2w, fc2b, fc3w, fc3b,
                       spatial, out0, hlast);
}